// Round 2
// baseline (365.619 us; speedup 1.0000x reference)
//
#include <hip/hip_runtime.h>

// x [32,64,64,64] f32, emb [64,1024] f32
// N = 131072 pixels, D = 64, K = 1024
// out = [ result: 8388608 f32 ][ argmin-as-f32: 131072 ]
//
// Strategy: block = 64 pixels x all 1024 k. 4 waves/block; wave w owns ks
// [256w, 256w+256) so e-row addresses are wave-uniform (SGPR loads, no LDS).
// x lives in LDS transposed [pixel][d] with XOR-swizzled 16B chunks; one
// ds_read_b128 (4 d's) feeds 64 FMAs (16 ks x 4 d). FP32 op order identical
// to the round-1 passing kernel => bit-identical distances/argmin.

__global__ void e2_kernel(const float* __restrict__ emb, float* __restrict__ e2) {
    int k = blockIdx.x * 64 + threadIdx.x;   // 16 blocks x 64
    float s = 0.f;
#pragma unroll
    for (int d = 0; d < 64; ++d) {
        float v = emb[d * 1024 + k];
        s = fmaf(v, v, s);
    }
    e2[k] = s;
}

__launch_bounds__(256)
__global__ void vq_kernel(const float* __restrict__ x,
                          const float* __restrict__ emb,
                          const float* __restrict__ e2,
                          float* __restrict__ outq,
                          float* __restrict__ outidx) {
    __shared__ float sx[64 * 64];    // [p][d], 16B-chunk XOR swizzle
    __shared__ float rbest[256];
    __shared__ int   ridx[256];
    __shared__ int   samin[64];

    const int tx = threadIdx.x;
    const int n0 = blockIdx.x * 64;      // 64 consecutive pixels, one (b,h) row
    const int bb = n0 >> 12;
    const int hw = n0 & 4095;
    const float* xbase = x + bb * 262144 + hw;   // + d*4096 + p

    // stage x: global [d][p] coalesced float4 -> LDS [p][d] swizzled.
    // swizzle: chunk position = (d>>2) ^ (p & 15)  (keeps 16B alignment,
    // spreads lanes over all 8 line-positions on read)
    for (int i = tx; i < 1024; i += 256) {
        int d = i >> 4;
        int p4 = (i & 15) << 2;
        float4 v = *(const float4*)(xbase + d * 4096 + p4);
        float va[4] = {v.x, v.y, v.z, v.w};
        int c = d >> 2;
#pragma unroll
        for (int j = 0; j < 4; ++j) {
            int p = p4 + j;
            sx[p * 64 + ((c ^ (p & 15)) << 2) + (d & 3)] = va[j];
        }
    }
    __syncthreads();

    const int lane = tx & 63;                               // pixel
    const int w = __builtin_amdgcn_readfirstlane(tx >> 6);  // wave id (SGPR)
    const int psw = lane & 15;
    const float* xrow = sx + lane * 64;

    float best = 3.4e38f;
    int bestk = 0;

#pragma unroll 1
    for (int kc = 0; kc < 16; ++kc) {
        const int k0 = (w << 8) + (kc << 4);   // wave-uniform k base
        float acc[16];
#pragma unroll
        for (int kk = 0; kk < 16; ++kk) acc[kk] = 0.f;

#pragma unroll
        for (int c = 0; c < 16; ++c) {
            float4 xv = *(const float4*)(xrow + ((c ^ psw) << 2));  // x[p][4c..4c+3]
            float xa[4] = {xv.x, xv.y, xv.z, xv.w};
#pragma unroll
            for (int dd = 0; dd < 4; ++dd) {
                const float* erow = emb + (c * 4 + dd) * 1024 + k0;  // uniform addr
                float4 ea = *(const float4*)(erow);
                float4 eb = *(const float4*)(erow + 4);
                float4 ec = *(const float4*)(erow + 8);
                float4 ed = *(const float4*)(erow + 12);
                float ev[16] = {ea.x, ea.y, ea.z, ea.w, eb.x, eb.y, eb.z, eb.w,
                                ec.x, ec.y, ec.z, ec.w, ed.x, ed.y, ed.z, ed.w};
#pragma unroll
                for (int kk = 0; kk < 16; ++kk)
                    acc[kk] = fmaf(xa[dd], ev[kk], acc[kk]);   // d ascending: same
            }                                                   // order as round 1
        }

        float4 q0 = *(const float4*)(e2 + k0);
        float4 q1 = *(const float4*)(e2 + k0 + 4);
        float4 q2 = *(const float4*)(e2 + k0 + 8);
        float4 q3 = *(const float4*)(e2 + k0 + 12);
        float e2v[16] = {q0.x, q0.y, q0.z, q0.w, q1.x, q1.y, q1.z, q1.w,
                         q2.x, q2.y, q2.z, q2.w, q3.x, q3.y, q3.z, q3.w};
#pragma unroll
        for (int kk = 0; kk < 16; ++kk) {
            float dist = fmaf(-2.f, acc[kk], e2v[kk]);
            if (dist < best) { best = dist; bestk = k0 + kk; }   // strict <: lowest k
        }
    }

    rbest[(w << 6) + lane] = best;
    ridx[(w << 6) + lane] = bestk;
    __syncthreads();

    if (tx < 64) {
        float bv = rbest[tx];
        int bk = ridx[tx];
#pragma unroll
        for (int g = 1; g < 4; ++g) {          // ascending wave = ascending k:
            float v = rbest[(g << 6) + tx];    // strict < keeps lowest k on ties
            int kk2 = ridx[(g << 6) + tx];
            if (v < bv) { bv = v; bk = kk2; }
        }
        samin[tx] = bk;
        outidx[n0 + tx] = (float)bk;
    }
    __syncthreads();

    // gather codebook rows -> output, coalesced over p
    const int p = tx & 63;
    const int drow = tx >> 6;
    const int amin = samin[p];
    float* obase = outq + bb * 262144 + hw + p;
#pragma unroll
    for (int it = 0; it < 16; ++it) {
        int d = (it << 2) + drow;
        obase[d * 4096] = emb[d * 1024 + amin];
    }
}

extern "C" void kernel_launch(void* const* d_in, const int* in_sizes, int n_in,
                              void* d_out, int out_size, void* d_ws, size_t ws_size,
                              hipStream_t stream) {
    const float* x = (const float*)d_in[0];
    const float* emb = (const float*)d_in[1];
    float* outq = (float*)d_out;
    float* outidx = outq + 8388608;   // 32*64*64*64
    float* e2 = (float*)d_ws;         // 1024 floats scratch

    e2_kernel<<<16, 64, 0, stream>>>(emb, e2);
    vq_kernel<<<2048, 256, 0, stream>>>(x, emb, e2, outq, outidx);
}

// Round 3
// 177.559 us; speedup vs baseline: 2.0591x; 2.0591x over previous
//
#include <hip/hip_runtime.h>

// x [32,64,64,64] f32, emb [64,1024] f32
// N = 131072 pixels, D = 64, K = 1024
// out = [ result: 8388608 f32 ][ argmin-as-f32: 131072 ]
//
// Round 3: split-precision f16 MFMA. x = xh + xl, e = eh + el (_Float16 each,
// ~22 combined mantissa bits). x.e = xl.el + xl.eh + xh.el + xh.eh accumulated
// small->large into one fp32 MFMA accumulator chain: abs d2 error ~1e-6, same
// class as the fp32-reorder error rounds 1/2 proved flip-free (absmax 0.0).
// dist = e2[k] - 2*x.e with e2 computed in exact fp32 (round-1 semantics).

using half8 = __attribute__((ext_vector_type(8))) _Float16;
using half4 = __attribute__((ext_vector_type(4))) _Float16;
using f32x4 = __attribute__((ext_vector_type(4))) float;

#define XPITCH 72   // halfs per x-row in LDS: 64 + 8 pad (144B = 36 banks)

// prep: e2[k] fp32 (ascending-d fmaf, same as passing rounds),
// embT hi/lo f16 [k][d] (k-major so B-fragments are contiguous 16B chunks)
__global__ void prep_kernel(const float* __restrict__ emb,
                            float* __restrict__ e2,
                            _Float16* __restrict__ eTh,
                            _Float16* __restrict__ eTl) {
    int k = blockIdx.x * 256 + threadIdx.x;   // 4 x 256 = 1024
    float s = 0.f;
#pragma unroll
    for (int c = 0; c < 8; ++c) {
        half8 hv, lv;
#pragma unroll
        for (int j = 0; j < 8; ++j) {
            float v = emb[(c * 8 + j) * 1024 + k];   // coalesced across lanes
            s = fmaf(v, v, s);
            _Float16 h = (_Float16)v;                // RN to 11 bits
            hv[j] = h;
            lv[j] = (_Float16)(v - (float)h);        // exact residual, RN
        }
        *(half8*)(eTh + k * 64 + c * 8) = hv;        // 16B stores
        *(half8*)(eTl + k * 64 + c * 8) = lv;
    }
    e2[k] = s;
}

__launch_bounds__(256)
__global__ void vq_kernel(const float* __restrict__ x,
                          const _Float16* __restrict__ eTh,
                          const _Float16* __restrict__ eTl,
                          const float* __restrict__ e2,
                          const float* __restrict__ emb,
                          float* __restrict__ outq,
                          float* __restrict__ outidx) {
    __shared__ _Float16 sxh[64 * XPITCH];
    __shared__ _Float16 sxl[64 * XPITCH];
    __shared__ float rbest[4 * 64];
    __shared__ int   ridx[4 * 64];
    __shared__ int   samin[64];

    const int tx = threadIdx.x;
    const int n0 = blockIdx.x * 64;     // 64 consecutive pixels (one b,h row)
    const int bb = n0 >> 12;
    const int hw = n0 & 4095;
    const float* xbase = x + bb * 262144 + hw;   // + d*4096 + p

    // ---- stage x -> LDS [p][d] as f16 hi/lo --------------------------------
    {
        const int p  = tx & 63;
        const int dg = (tx >> 6) << 2;            // this thread's 4-d group
#pragma unroll
        for (int it = 0; it < 4; ++it) {
            int d0 = it * 16 + dg;
            float v0 = xbase[(d0 + 0) * 4096 + p];   // coalesced per d
            float v1 = xbase[(d0 + 1) * 4096 + p];
            float v2 = xbase[(d0 + 2) * 4096 + p];
            float v3 = xbase[(d0 + 3) * 4096 + p];
            _Float16 h0 = (_Float16)v0, h1 = (_Float16)v1,
                     h2 = (_Float16)v2, h3 = (_Float16)v3;
            half4 hv = {h0, h1, h2, h3};
            half4 lv = {(_Float16)(v0 - (float)h0), (_Float16)(v1 - (float)h1),
                        (_Float16)(v2 - (float)h2), (_Float16)(v3 - (float)h3)};
            *(half4*)(sxh + p * XPITCH + d0) = hv;   // 8B LDS stores
            *(half4*)(sxl + p * XPITCH + d0) = lv;
        }
    }
    __syncthreads();

    const int lane = tx & 63;
    const int w    = tx >> 6;
    const int r16  = lane & 15;     // A-row / B-col / C-col index
    const int q    = lane >> 4;     // quad

    // ---- A-fragments (persistent): A[m=r16][k=q*8+j], 4 Mtiles x 2 ksteps --
    half8 ah[4][2], al[4][2];
#pragma unroll
    for (int mt = 0; mt < 4; ++mt)
#pragma unroll
        for (int s = 0; s < 2; ++s) {
            const _Float16* ap = sxh + (mt * 16 + r16) * XPITCH + s * 32 + q * 8;
            const _Float16* lp = sxl + (mt * 16 + r16) * XPITCH + s * 32 + q * 8;
            ah[mt][s] = *(const half8*)ap;    // ds_read_b128, pad-balanced
            al[mt][s] = *(const half8*)lp;
        }

    float best[16];
    int   bestk[16];
#pragma unroll
    for (int i = 0; i < 16; ++i) { best[i] = 3.4e38f; bestk[i] = 0; }

    const int kw = w << 8;          // wave's k base (256 ks per wave)

#pragma unroll 2
    for (int t = 0; t < 16; ++t) {
        const int kl = kw + (t << 4) + r16;        // this lane's k this Ntile
        const _Float16* bhp = eTh + kl * 64 + q * 8;
        const _Float16* blp = eTl + kl * 64 + q * 8;
        half8 bh0 = *(const half8*)(bhp);          // B[k=q*8+j][n=r16]
        half8 bh1 = *(const half8*)(bhp + 32);
        half8 bl0 = *(const half8*)(blp);
        half8 bl1 = *(const half8*)(blp + 32);
        float e2v = e2[kl];

        f32x4 acc[4];
#pragma unroll
        for (int mt = 0; mt < 4; ++mt) {
            f32x4 a = {0.f, 0.f, 0.f, 0.f};
            // small -> large accumulation
            a = __builtin_amdgcn_mfma_f32_16x16x32_f16(al[mt][0], bl0, a, 0, 0, 0);
            a = __builtin_amdgcn_mfma_f32_16x16x32_f16(al[mt][1], bl1, a, 0, 0, 0);
            a = __builtin_amdgcn_mfma_f32_16x16x32_f16(al[mt][0], bh0, a, 0, 0, 0);
            a = __builtin_amdgcn_mfma_f32_16x16x32_f16(al[mt][1], bh1, a, 0, 0, 0);
            a = __builtin_amdgcn_mfma_f32_16x16x32_f16(ah[mt][0], bl0, a, 0, 0, 0);
            a = __builtin_amdgcn_mfma_f32_16x16x32_f16(ah[mt][1], bl1, a, 0, 0, 0);
            a = __builtin_amdgcn_mfma_f32_16x16x32_f16(ah[mt][0], bh0, a, 0, 0, 0);
            a = __builtin_amdgcn_mfma_f32_16x16x32_f16(ah[mt][1], bh1, a, 0, 0, 0);
            acc[mt] = a;
        }

#pragma unroll
        for (int mt = 0; mt < 4; ++mt)
#pragma unroll
            for (int rr = 0; rr < 4; ++rr) {
                float dist = fmaf(-2.f, acc[mt][rr], e2v);
                int i = mt * 4 + rr;
                if (dist < best[i]) { best[i] = dist; bestk[i] = kl; }
            }
    }

    // ---- per-pixel argmin: reduce over the 16 lanes sharing a C-row --------
    // pixel p = mt*16 + q*4 + rr lives in lanes {q*16 .. q*16+15} reg (mt,rr)
#pragma unroll
    for (int i = 0; i < 16; ++i) {
        float bv = best[i];
        int   bk = bestk[i];
#pragma unroll
        for (int m = 1; m < 16; m <<= 1) {
            float ov = __shfl_xor(bv, m, 64);
            int   ok = __shfl_xor(bk, m, 64);
            if (ov < bv || (ov == bv && ok < bk)) { bv = ov; bk = ok; }
        }
        best[i] = bv;
        bestk[i] = bk;
    }
    if (r16 == 0) {
#pragma unroll
        for (int mt = 0; mt < 4; ++mt)
#pragma unroll
            for (int rr = 0; rr < 4; ++rr) {
                int p = mt * 16 + q * 4 + rr;
                rbest[w * 64 + p] = best[mt * 4 + rr];
                ridx[w * 64 + p]  = bestk[mt * 4 + rr];
            }
    }
    __syncthreads();

    // ---- cross-wave merge (ascending wave = ascending k) -------------------
    if (tx < 64) {
        float bv = rbest[tx];
        int   bk = ridx[tx];
#pragma unroll
        for (int g = 1; g < 4; ++g) {
            float v = rbest[g * 64 + tx];
            int   kk = ridx[g * 64 + tx];
            if (v < bv || (v == bv && kk < bk)) { bv = v; bk = kk; }
        }
        samin[tx] = bk;
        outidx[n0 + tx] = (float)bk;
    }
    __syncthreads();

    // ---- gather exact fp32 codebook rows -> output, coalesced over p -------
    const int p = tx & 63;
    const int drow = tx >> 6;
    const int amin = samin[p];
    float* obase = outq + bb * 262144 + hw + p;
#pragma unroll
    for (int it = 0; it < 16; ++it) {
        int d = (it << 2) + drow;
        obase[d * 4096] = emb[d * 1024 + amin];
    }
}

extern "C" void kernel_launch(void* const* d_in, const int* in_sizes, int n_in,
                              void* d_out, int out_size, void* d_ws, size_t ws_size,
                              hipStream_t stream) {
    const float* x   = (const float*)d_in[0];
    const float* emb = (const float*)d_in[1];
    float* outq   = (float*)d_out;
    float* outidx = outq + 8388608;            // 32*64*64*64

    float*    e2  = (float*)d_ws;                               // 4 KB
    _Float16* eTh = (_Float16*)((char*)d_ws + 4096);            // 128 KB
    _Float16* eTl = (_Float16*)((char*)d_ws + 4096 + 131072);   // 128 KB

    prep_kernel<<<4, 256, 0, stream>>>(emb, e2, eTh, eTl);
    vq_kernel<<<2048, 256, 0, stream>>>(x, eTh, eTl, e2, emb, outq, outidx);
}

// Round 4
// 161.237 us; speedup vs baseline: 2.2676x; 1.1012x over previous
//
#include <hip/hip_runtime.h>

// x [32,64,64,64] f32, emb [64,1024] f32
// N = 131072 pixels, D = 64, K = 1024
// out = [ result: 8388608 f32 ][ argmin-as-f32: 131072 ]
//
// Round 4: same exact split-f16 MFMA math as round 3 (absmax 0.0), plus:
//  - A-fragments pinned in VGPRs via asm barrier (round 3's VGPR_Count=76
//    proved the compiler was re-reading them from LDS every t-iter)
//  - explicit register double-buffer for B-fragments + e2 (one-iter prefetch)
//  - prep kernel spread over 16 blocks

using half8 = __attribute__((ext_vector_type(8))) _Float16;
using half4 = __attribute__((ext_vector_type(4))) _Float16;
using f32x4 = __attribute__((ext_vector_type(4))) float;

#define XPITCH 72   // halfs per x-row in LDS: 64 + 8 pad

__global__ void prep_kernel(const float* __restrict__ emb,
                            float* __restrict__ e2,
                            _Float16* __restrict__ eTh,
                            _Float16* __restrict__ eTl) {
    int k = blockIdx.x * 64 + threadIdx.x;   // 16 blocks x 64
    float s = 0.f;
#pragma unroll
    for (int c = 0; c < 8; ++c) {
        half8 hv, lv;
#pragma unroll
        for (int j = 0; j < 8; ++j) {
            float v = emb[(c * 8 + j) * 1024 + k];   // coalesced across lanes
            s = fmaf(v, v, s);                       // ascending-d fmaf (exact
            _Float16 h = (_Float16)v;                //  order from round 1)
            hv[j] = h;
            lv[j] = (_Float16)(v - (float)h);        // exact residual
        }
        *(half8*)(eTh + k * 64 + c * 8) = hv;
        *(half8*)(eTl + k * 64 + c * 8) = lv;
    }
    e2[k] = s;
}

__launch_bounds__(256)
__global__ void vq_kernel(const float* __restrict__ x,
                          const _Float16* __restrict__ eTh,
                          const _Float16* __restrict__ eTl,
                          const float* __restrict__ e2,
                          const float* __restrict__ emb,
                          float* __restrict__ outq,
                          float* __restrict__ outidx) {
    __shared__ _Float16 sxh[64 * XPITCH];
    __shared__ _Float16 sxl[64 * XPITCH];
    __shared__ float rbest[256];
    __shared__ int   ridx[256];
    __shared__ int   samin[64];

    const int tx = threadIdx.x;
    const int n0 = blockIdx.x * 64;
    const int bb = n0 >> 12;
    const int hw = n0 & 4095;
    const float* xbase = x + bb * 262144 + hw;

    // ---- stage x -> LDS [p][d] as f16 hi/lo --------------------------------
    {
        const int p  = tx & 63;
        const int dg = (tx >> 6) << 2;
#pragma unroll
        for (int it = 0; it < 4; ++it) {
            int d0 = it * 16 + dg;
            float v0 = xbase[(d0 + 0) * 4096 + p];
            float v1 = xbase[(d0 + 1) * 4096 + p];
            float v2 = xbase[(d0 + 2) * 4096 + p];
            float v3 = xbase[(d0 + 3) * 4096 + p];
            _Float16 h0 = (_Float16)v0, h1 = (_Float16)v1,
                     h2 = (_Float16)v2, h3 = (_Float16)v3;
            half4 hv = {h0, h1, h2, h3};
            half4 lv = {(_Float16)(v0 - (float)h0), (_Float16)(v1 - (float)h1),
                        (_Float16)(v2 - (float)h2), (_Float16)(v3 - (float)h3)};
            *(half4*)(sxh + p * XPITCH + d0) = hv;
            *(half4*)(sxl + p * XPITCH + d0) = lv;
        }
    }
    __syncthreads();

    const int lane = tx & 63;
    const int w    = tx >> 6;
    const int r16  = lane & 15;
    const int q    = lane >> 4;

    // ---- A-fragments, loaded ONCE and pinned in VGPRs ----------------------
    half8 ah[4][2], al[4][2];
#pragma unroll
    for (int mt = 0; mt < 4; ++mt)
#pragma unroll
        for (int s = 0; s < 2; ++s) {
            ah[mt][s] = *(const half8*)(sxh + (mt * 16 + r16) * XPITCH + s * 32 + q * 8);
            al[mt][s] = *(const half8*)(sxl + (mt * 16 + r16) * XPITCH + s * 32 + q * 8);
        }
#pragma unroll
    for (int mt = 0; mt < 4; ++mt)
#pragma unroll
        for (int s = 0; s < 2; ++s) {
            asm volatile("" : "+v"(ah[mt][s]));   // forbid LDS remat in loop
            asm volatile("" : "+v"(al[mt][s]));
        }

    float best[16];
    int   bestk[16];
#pragma unroll
    for (int i = 0; i < 16; ++i) { best[i] = 3.4e38f; bestk[i] = 0; }

    const int kw = w << 8;
    const _Float16* bhbase = eTh + (kw + r16) * 64 + q * 8;
    const _Float16* blbase = eTl + (kw + r16) * 64 + q * 8;
    const float*    e2base = e2 + kw + r16;

    half8 pbh0, pbh1, pbl0, pbl1; float pe2;
    half8 qbh0, qbh1, qbl0, qbl1; float qe2;

#define LOADSET(BH0, BH1, BL0, BL1, E2V, TT)                                  \
    {                                                                         \
        const int off_ = (TT) << 10;  /* 16 k-rows * 64 halfs */              \
        BH0 = *(const half8*)(bhbase + off_);                                 \
        BH1 = *(const half8*)(bhbase + off_ + 32);                            \
        BL0 = *(const half8*)(blbase + off_);                                 \
        BL1 = *(const half8*)(blbase + off_ + 32);                            \
        E2V = e2base[(TT) << 4];                                              \
    }

#define COMPUTE(BH0, BH1, BL0, BL1, E2V, TT)                                  \
    {                                                                         \
        const int klc_ = kw + ((TT) << 4) + r16;                              \
        _Pragma("unroll")                                                     \
        for (int mt = 0; mt < 4; ++mt) {                                      \
            f32x4 a = {0.f, 0.f, 0.f, 0.f};                                   \
            a = __builtin_amdgcn_mfma_f32_16x16x32_f16(al[mt][0], BL0, a, 0, 0, 0); \
            a = __builtin_amdgcn_mfma_f32_16x16x32_f16(al[mt][1], BL1, a, 0, 0, 0); \
            a = __builtin_amdgcn_mfma_f32_16x16x32_f16(al[mt][0], BH0, a, 0, 0, 0); \
            a = __builtin_amdgcn_mfma_f32_16x16x32_f16(al[mt][1], BH1, a, 0, 0, 0); \
            a = __builtin_amdgcn_mfma_f32_16x16x32_f16(ah[mt][0], BL0, a, 0, 0, 0); \
            a = __builtin_amdgcn_mfma_f32_16x16x32_f16(ah[mt][1], BL1, a, 0, 0, 0); \
            a = __builtin_amdgcn_mfma_f32_16x16x32_f16(ah[mt][0], BH0, a, 0, 0, 0); \
            a = __builtin_amdgcn_mfma_f32_16x16x32_f16(ah[mt][1], BH1, a, 0, 0, 0); \
            _Pragma("unroll")                                                 \
            for (int rr = 0; rr < 4; ++rr) {                                  \
                float dist_ = fmaf(-2.f, a[rr], E2V);                         \
                int i_ = mt * 4 + rr;                                         \
                if (dist_ < best[i_]) { best[i_] = dist_; bestk[i_] = klc_; } \
            }                                                                 \
        }                                                                     \
    }

    LOADSET(pbh0, pbh1, pbl0, pbl1, pe2, 0);
#pragma unroll 1
    for (int t = 0; t < 16; t += 2) {
        LOADSET(qbh0, qbh1, qbl0, qbl1, qe2, t + 1);
        COMPUTE(pbh0, pbh1, pbl0, pbl1, pe2, t);
        LOADSET(pbh0, pbh1, pbl0, pbl1, pe2, (t + 2) & 15);  // wrap: valid, unused at t=14
        COMPUTE(qbh0, qbh1, qbl0, qbl1, qe2, t + 1);
    }

    // ---- per-pixel argmin: reduce over the 16 lanes sharing a C-row --------
#pragma unroll
    for (int i = 0; i < 16; ++i) {
        float bv = best[i];
        int   bk = bestk[i];
#pragma unroll
        for (int m = 1; m < 16; m <<= 1) {
            float ov = __shfl_xor(bv, m, 64);
            int   ok = __shfl_xor(bk, m, 64);
            if (ov < bv || (ov == bv && ok < bk)) { bv = ov; bk = ok; }
        }
        best[i] = bv;
        bestk[i] = bk;
    }
    if (r16 == 0) {
#pragma unroll
        for (int mt = 0; mt < 4; ++mt)
#pragma unroll
            for (int rr = 0; rr < 4; ++rr) {
                int p = mt * 16 + q * 4 + rr;
                rbest[w * 64 + p] = best[mt * 4 + rr];
                ridx[w * 64 + p]  = bestk[mt * 4 + rr];
            }
    }
    __syncthreads();

    // ---- cross-wave merge (ascending wave = ascending k) -------------------
    if (tx < 64) {
        float bv = rbest[tx];
        int   bk = ridx[tx];
#pragma unroll
        for (int g = 1; g < 4; ++g) {
            float v  = rbest[g * 64 + tx];
            int   kk = ridx[g * 64 + tx];
            if (v < bv || (v == bv && kk < bk)) { bv = v; bk = kk; }
        }
        samin[tx] = bk;
        outidx[n0 + tx] = (float)bk;
    }
    __syncthreads();

    // ---- gather exact fp32 codebook rows -> output, coalesced over p -------
    const int p = tx & 63;
    const int drow = tx >> 6;
    const int amin = samin[p];
    float* obase = outq + bb * 262144 + hw + p;
#pragma unroll
    for (int it = 0; it < 16; ++it) {
        int d = (it << 2) + drow;
        obase[d * 4096] = emb[d * 1024 + amin];
    }
}

extern "C" void kernel_launch(void* const* d_in, const int* in_sizes, int n_in,
                              void* d_out, int out_size, void* d_ws, size_t ws_size,
                              hipStream_t stream) {
    const float* x   = (const float*)d_in[0];
    const float* emb = (const float*)d_in[1];
    float* outq   = (float*)d_out;
    float* outidx = outq + 8388608;            // 32*64*64*64

    float*    e2  = (float*)d_ws;                               // 4 KB
    _Float16* eTh = (_Float16*)((char*)d_ws + 4096);            // 128 KB
    _Float16* eTl = (_Float16*)((char*)d_ws + 4096 + 131072);   // 128 KB

    prep_kernel<<<16, 64, 0, stream>>>(emb, e2, eTh, eTl);
    vq_kernel<<<2048, 256, 0, stream>>>(x, eTh, eTl, e2, emb, outq, outidx);
}